// Round 1
// baseline (143.677 us; speedup 1.0000x reference)
//
#include <hip/hip_runtime.h>
#include <math.h>

#define C_DIM 64
#define HW_DIM 1024
#define N_TOT 4096
#define IMG 2048
#define NEG_INF (-1e30f)

// ---------------- Kernel 1: reciprocal L2 norms per position ----------------
// Position n -> elements at ((n>>10)<<16) + c*1024 + (n&1023). Coalesced
// across lanes for each c (consecutive n -> consecutive hw).
__global__ __launch_bounds__(256) void norms_kernel(
    const float* __restrict__ s, const float* __restrict__ t,
    float* __restrict__ rs, float* __restrict__ rt) {
    int n = blockIdx.x * 256 + threadIdx.x;
    int base = ((n >> 10) << 16) + (n & 1023);
    float ss = 0.f, tt = 0.f;
#pragma unroll
    for (int c = 0; c < C_DIM; ++c) {
        float a = s[base + c * HW_DIM];
        float b = t[base + c * HW_DIM];
        ss = fmaf(a, a, ss);
        tt = fmaf(b, b, tt);
    }
    rs[n] = 1.f / fmaxf(sqrtf(ss), 1e-12f);
    rt[n] = 1.f / fmaxf(sqrtf(tt), 1e-12f);
}

// ---- Kernel 2: fused block-diagonal logits + masked softmax partials ----
// grid.x = 512: rb = bid>>3 (64-row block), jc = bid&7 (256-col chunk within
// the row block's image). 256 threads as 16x16; each thread owns a 4x4 output
// micro-tile. LDS tiles are [c][pos] so both A and B fragments are float4
// reads, conflict-free (broadcast + 2-way, which is free on CDNA4).
__global__ __launch_bounds__(256) void logits_stats_kernel(
    const float* __restrict__ s, const float* __restrict__ t,
    const int* __restrict__ labels, const float* __restrict__ rs,
    const float* __restrict__ rt, float4* __restrict__ stats) {

    const int rb = blockIdx.x >> 3;
    const int jc = blockIdx.x & 7;
    const int img = rb >> 5;          // 32 row-blocks per image
    const int i0 = rb * 64;
    const int jbase0 = img * IMG + jc * 256;

    const int tid = threadIdx.x;
    const int tx = tid & 15;
    const int ty = tid >> 4;

    __shared__ __align__(16) float lds_sf[C_DIM][68];
    __shared__ __align__(16) float lds_tf[C_DIM][68];
    __shared__ __align__(16) float lds_rt[256];
    __shared__ int lds_lab[256];
    __shared__ __align__(16) float lds_rs[64];

    if (tid < 64) lds_rs[tid] = rs[i0 + tid];
    lds_rt[tid] = rt[jbase0 + tid];
    lds_lab[tid] = labels[jbase0 + tid];
    __syncthreads();

    // Stage normalized student tile: 64 rows x 64 c, float4 everywhere.
    {
        const int bvi = ((i0 >> 10) << 16) + (i0 & 1023);
        const int cq = tid >> 4;          // 0..15
        const int nj = (tid & 15) << 2;   // 0..60
        float4 rv = *(const float4*)&lds_rs[nj];
#pragma unroll
        for (int k = 0; k < 4; ++k) {
            int c = cq + k * 16;
            float4 v = *(const float4*)(s + bvi + c * HW_DIM + nj);
            v.x *= rv.x; v.y *= rv.y; v.z *= rv.z; v.w *= rv.w;
            *(float4*)&lds_sf[c][nj] = v;
        }
    }

    int lab_i[4];
#pragma unroll
    for (int rr = 0; rr < 4; ++rr) lab_i[rr] = labels[i0 + ty * 4 + rr];

    float m_run[4], s_run[4], A_run[4], c_run[4];
#pragma unroll
    for (int rr = 0; rr < 4; ++rr) {
        m_run[rr] = NEG_INF; s_run[rr] = 0.f; A_run[rr] = 0.f; c_run[rr] = 0.f;
    }

    for (int tile = 0; tile < 4; ++tile) {
        const int jb = jbase0 + tile * 64;
        __syncthreads();  // previous tile's compute done before overwrite
        {
            const int bvj = ((jb >> 10) << 16) + (jb & 1023);
            const int cq = tid >> 4;
            const int nj = (tid & 15) << 2;
            float4 rv = *(const float4*)&lds_rt[tile * 64 + nj];
#pragma unroll
            for (int k = 0; k < 4; ++k) {
                int c = cq + k * 16;
                float4 v = *(const float4*)(t + bvj + c * HW_DIM + nj);
                v.x *= rv.x; v.y *= rv.y; v.z *= rv.z; v.w *= rv.w;
                *(float4*)&lds_tf[c][nj] = v;
            }
        }
        __syncthreads();

        float acc[4][4];
#pragma unroll
        for (int a = 0; a < 4; ++a)
#pragma unroll
            for (int b = 0; b < 4; ++b) acc[a][b] = 0.f;

#pragma unroll 8
        for (int c = 0; c < C_DIM; ++c) {
            float4 av = *(const float4*)&lds_sf[c][ty << 2];
            float4 bv = *(const float4*)&lds_tf[c][tx << 2];
            const float aa[4] = {av.x, av.y, av.z, av.w};
            const float bb[4] = {bv.x, bv.y, bv.z, bv.w};
#pragma unroll
            for (int a = 0; a < 4; ++a)
#pragma unroll
                for (int b = 0; b < 4; ++b)
                    acc[a][b] = fmaf(aa[a], bb[b], acc[a][b]);
        }

        // Fused epilogue: mask + online (max,sumexp) + numerator sums.
#pragma unroll
        for (int rr = 0; rr < 4; ++rr) {
            const int i_g = i0 + ty * 4 + rr;
            float vals[4];
            float lm = NEG_INF;
#pragma unroll
            for (int jj = 0; jj < 4; ++jj) {
                const int j_g = jb + tx * 4 + jj;
                float logit = acc[rr][jj] * 10.f;  // 1/TEMPERATURE
                bool self = (j_g == i_g);
                float v = self ? NEG_INF : logit;
                vals[jj] = v;
                lm = fmaxf(lm, v);
                if (!self && lds_lab[tile * 64 + tx * 4 + jj] == lab_i[rr]) {
                    A_run[rr] += logit;
                    c_run[rr] += 1.f;
                }
            }
            float M = fmaxf(m_run[rr], lm);
            float sn = s_run[rr] * __expf(m_run[rr] - M);
#pragma unroll
            for (int jj = 0; jj < 4; ++jj) sn += __expf(vals[jj] - M);
            m_run[rr] = M;
            s_run[rr] = sn;
        }
    }

    // Reduce across the 16 tx lanes (lane bits 0..3) per row group.
#pragma unroll
    for (int off = 1; off < 16; off <<= 1) {
#pragma unroll
        for (int rr = 0; rr < 4; ++rr) {
            float m2 = __shfl_xor(m_run[rr], off, 64);
            float s2 = __shfl_xor(s_run[rr], off, 64);
            float A2 = __shfl_xor(A_run[rr], off, 64);
            float c2 = __shfl_xor(c_run[rr], off, 64);
            float M = fmaxf(m_run[rr], m2);
            s_run[rr] = s_run[rr] * __expf(m_run[rr] - M) + s2 * __expf(m2 - M);
            m_run[rr] = M;
            A_run[rr] += A2;
            c_run[rr] += c2;
        }
    }

    if (tx == 0) {
#pragma unroll
        for (int rr = 0; rr < 4; ++rr) {
            const int i_g = i0 + ty * 4 + rr;
            stats[i_g * 8 + jc] = make_float4(m_run[rr], s_run[rr], A_run[rr], c_run[rr]);
        }
    }
}

// -------- Kernel 3: merge chunk partials per row, global loss reduce --------
__global__ __launch_bounds__(256) void finalize_kernel(
    const float4* __restrict__ stats, const int* __restrict__ labels,
    float* __restrict__ out) {
    const int tid = threadIdx.x;
    float sum_mlpp = 0.f, sum_valid = 0.f, sum_nbv = 0.f;
    for (int r = tid; r < N_TOT; r += 256) {
        float m = NEG_INF, sexp = 0.f, A = 0.f, cnt = 0.f;
#pragma unroll
        for (int c = 0; c < 8; ++c) {
            float4 v = stats[r * 8 + c];
            float M = fmaxf(m, v.x);
            sexp = sexp * __expf(m - M) + v.y * __expf(v.x - M);
            m = M;
            A += v.z;
            cnt += v.w;
        }
        if (cnt > 0.5f) {  // numerator_sums > EPS  (counts are integers)
            float lse = m + __logf(sexp);
            float mlpp = (A - cnt * lse) / (cnt + 1e-8f);
            sum_mlpp += mlpp;
            sum_valid += 1.f;
            if (labels[r] != 0) sum_nbv += 1.f;
        }
    }
    __shared__ float red0[256], red1[256], red2[256];
    red0[tid] = sum_mlpp; red1[tid] = sum_valid; red2[tid] = sum_nbv;
    __syncthreads();
    for (int off = 128; off > 0; off >>= 1) {
        if (tid < off) {
            red0[tid] += red0[tid + off];
            red1[tid] += red1[tid + off];
            red2[tid] += red2[tid + off];
        }
        __syncthreads();
    }
    if (tid == 0) {
        float loss = -red0[0] / red1[0];
        float nbv = red2[0];
        out[0] = loss * nbv / (nbv + 1e-8f);
    }
}

extern "C" void kernel_launch(void* const* d_in, const int* in_sizes, int n_in,
                              void* d_out, int out_size, void* d_ws, size_t ws_size,
                              hipStream_t stream) {
    const float* s = (const float*)d_in[0];
    const float* t = (const float*)d_in[1];
    const int* labels = (const int*)d_in[2];
    float* out = (float*)d_out;
    float* ws = (float*)d_ws;

    float* rs = ws;             // 4096 floats
    float* rt = ws + 4096;      // 4096 floats
    float4* stats = (float4*)(ws + 8192);  // 4096 * 8 float4 = 512 KB

    hipLaunchKernelGGL(norms_kernel, dim3(N_TOT / 256), dim3(256), 0, stream,
                       s, t, rs, rt);
    hipLaunchKernelGGL(logits_stats_kernel, dim3(512), dim3(256), 0, stream,
                       s, t, labels, rs, rt, stats);
    hipLaunchKernelGGL(finalize_kernel, dim3(1), dim3(256), 0, stream,
                       stats, labels, out);
}

// Round 2
// 85.825 us; speedup vs baseline: 1.6741x; 1.6741x over previous
//
#include <hip/hip_runtime.h>
#include <math.h>

#define C_DIM 64
#define HW_DIM 1024
#define N_TOT 4096
#define IMG 2048
#define NEG_INF (-1e30f)

// ---------------- Kernel 1: reciprocal L2 norms (parallelized) ----------------
// 128 blocks: blocks 0-63 handle student positions, 64-127 teacher.
// Block covers 64 positions; 4 c-chunks of 16 per position; LDS reduce.
// Also zeroes the finalize kernel's atomic accumulators (ws is poisoned).
__global__ __launch_bounds__(256) void norms_kernel(
    const float* __restrict__ s, const float* __restrict__ t,
    float* __restrict__ rs, float* __restrict__ rt,
    float* __restrict__ accums) {
    const int b = blockIdx.x;
    const int pos = threadIdx.x & 63;
    const int chunk = threadIdx.x >> 6;   // 0..3
    const int n = ((b & 63) << 6) + pos;
    const float* __restrict__ src = (b >= 64) ? t : s;
    const int base = ((n >> 10) << 16) + (n & 1023);
    float ss = 0.f;
#pragma unroll
    for (int k = 0; k < 16; ++k) {
        float a = src[base + ((chunk << 4) + k) * HW_DIM];
        ss = fmaf(a, a, ss);
    }
    __shared__ float red[4][64];
    red[chunk][pos] = ss;
    __syncthreads();
    if (threadIdx.x < 64) {
        float v = red[0][pos] + red[1][pos] + red[2][pos] + red[3][pos];
        float r = 1.f / fmaxf(sqrtf(v), 1e-12f);
        if (b >= 64) rt[n] = r; else rs[n] = r;
    }
    if (b == 0 && threadIdx.x < 8) accums[threadIdx.x] = 0.f;
}

// ---- Kernel 2: block-diagonal logits + masked softmax partials ----
// 256 blocks: rb = bid>>3 (32 blocks of 128 rows), jc = bid&7 (256-col chunk
// inside the row block's image). Block tile 128 rows x 256 cols, processed as
// two 128-col halves. 256 threads as 16x16, each owns an 8x8 micro-tile
// (64 FMA per 4 ds_read_b128 -> LDS demand ~ FMA wall). B tile stored with a
// +4-per-32 swizzle so the tx-strided b128 reads are 2-way (free) not 4-way.
__global__ __launch_bounds__(256, 2) void logits_stats_kernel(
    const float* __restrict__ s, const float* __restrict__ t,
    const int* __restrict__ labels, const float* __restrict__ rs,
    const float* __restrict__ rt, float4* __restrict__ stats) {

    const int rb = blockIdx.x >> 3;
    const int jc = blockIdx.x & 7;
    const int img = rb >> 4;            // 16 row-blocks of 128 per image
    const int i0 = rb * 128;
    const int jbase0 = img * IMG + jc * 256;

    const int tid = threadIdx.x;
    const int tx = tid & 15;
    const int ty = tid >> 4;

    __shared__ __align__(16) float lds_a[C_DIM][132];   // [c][row]
    __shared__ __align__(16) float lds_b[C_DIM][144];   // [c][swizzled col]
    __shared__ __align__(16) float lds_rsa[128];
    __shared__ __align__(16) float lds_rtb[256];
    __shared__ __align__(16) int lds_labj[256];

    if (tid < 128) lds_rsa[tid] = rs[i0 + tid];
    lds_rtb[tid] = rt[jbase0 + tid];
    lds_labj[tid] = labels[jbase0 + tid];
    __syncthreads();

    // Stage normalized A tile: 128 rows x 64 c, [c][row], float4 everywhere.
    {
        const int bvi = ((i0 >> 10) << 16) + (i0 & 1023);
        const int pos4 = (tid & 31) << 2;    // 0..124
        const int c0 = tid >> 5;             // 0..7
        float4 rv = *(const float4*)&lds_rsa[pos4];
#pragma unroll
        for (int k = 0; k < 8; ++k) {
            int c = c0 + (k << 3);
            float4 v = *(const float4*)(s + bvi + c * HW_DIM + pos4);
            v.x *= rv.x; v.y *= rv.y; v.z *= rv.z; v.w *= rv.w;
            *(float4*)&lds_a[c][pos4] = v;
        }
    }

    int lab_i[8];
#pragma unroll
    for (int rr = 0; rr < 8; ++rr) lab_i[rr] = labels[i0 + ty * 8 + rr];

    float m_run[8], s_run[8], A_run[8], c_run[8];
#pragma unroll
    for (int rr = 0; rr < 8; ++rr) {
        m_run[rr] = NEG_INF; s_run[rr] = 0.f; A_run[rr] = 0.f; c_run[rr] = 0.f;
    }

    const int arow = ty << 3;            // this thread's first A row
    const int bo = tx << 3;              // this thread's first B col (unswizzled)
    const int bos = bo + ((bo >> 5) << 2);  // swizzled LDS offset

    for (int jh = 0; jh < 2; ++jh) {
        const int colh = jh * 128;                 // col offset within 256-chunk
        const int jb_img = jbase0 + colh;          // global col base
        __syncthreads();   // A staged (jh=0) / previous half's compute done
        {
            const int bvj = ((jb_img >> 10) << 16) + (jb_img & 1023);
            const int pos4 = (tid & 31) << 2;
            const int c0 = tid >> 5;
            float4 rv = *(const float4*)&lds_rtb[colh + pos4];
            const int sp = pos4 + ((pos4 >> 5) << 2);
#pragma unroll
            for (int k = 0; k < 8; ++k) {
                int c = c0 + (k << 3);
                float4 v = *(const float4*)(t + bvj + c * HW_DIM + pos4);
                v.x *= rv.x; v.y *= rv.y; v.z *= rv.z; v.w *= rv.w;
                *(float4*)&lds_b[c][sp] = v;
            }
        }
        __syncthreads();

        // labels for this thread's 8 cols, from LDS once (reused for 8 rows)
        int labj[8];
        {
            int4 l0 = *(const int4*)&lds_labj[colh + bo];
            int4 l1 = *(const int4*)&lds_labj[colh + bo + 4];
            labj[0] = l0.x; labj[1] = l0.y; labj[2] = l0.z; labj[3] = l0.w;
            labj[4] = l1.x; labj[5] = l1.y; labj[6] = l1.z; labj[7] = l1.w;
        }

        float acc[8][8];
#pragma unroll
        for (int a = 0; a < 8; ++a)
#pragma unroll
            for (int b2 = 0; b2 < 8; ++b2) acc[a][b2] = 0.f;

#pragma unroll 4
        for (int c = 0; c < C_DIM; ++c) {
            float4 a0 = *(const float4*)&lds_a[c][arow];
            float4 a1 = *(const float4*)&lds_a[c][arow + 4];
            float4 b0 = *(const float4*)&lds_b[c][bos];
            float4 b1 = *(const float4*)&lds_b[c][bos + 4];
            const float ar[8] = {a0.x, a0.y, a0.z, a0.w, a1.x, a1.y, a1.z, a1.w};
            const float br[8] = {b0.x, b0.y, b0.z, b0.w, b1.x, b1.y, b1.z, b1.w};
#pragma unroll
            for (int a = 0; a < 8; ++a)
#pragma unroll
                for (int b2 = 0; b2 < 8; ++b2)
                    acc[a][b2] = fmaf(ar[a], br[b2], acc[a][b2]);
        }

        // Fused epilogue: mask + numerator sums + online (max, sumexp).
#pragma unroll
        for (int rr = 0; rr < 8; ++rr) {
            const int i_g = i0 + arow + rr;
            const int li = lab_i[rr];
            float vals[8];
            float lm = NEG_INF;
#pragma unroll
            for (int jj = 0; jj < 8; ++jj) {
                const int j_g = jb_img + bo + jj;
                float logit = acc[rr][jj] * 10.f;  // 1/TEMPERATURE
                bool self = (j_g == i_g);
                float v = self ? NEG_INF : logit;
                vals[jj] = v;
                lm = fmaxf(lm, v);
                if (!self && labj[jj] == li) {
                    A_run[rr] += logit;
                    c_run[rr] += 1.f;
                }
            }
            float M = fmaxf(m_run[rr], lm);
            float sn = s_run[rr] * __expf(m_run[rr] - M);
#pragma unroll
            for (int jj = 0; jj < 8; ++jj) sn += __expf(vals[jj] - M);
            m_run[rr] = M;
            s_run[rr] = sn;
        }
    }

    // Reduce across the 16 tx lanes (low 4 lane bits) per row.
#pragma unroll
    for (int off = 1; off < 16; off <<= 1) {
#pragma unroll
        for (int rr = 0; rr < 8; ++rr) {
            float m2 = __shfl_xor(m_run[rr], off, 64);
            float s2 = __shfl_xor(s_run[rr], off, 64);
            float A2 = __shfl_xor(A_run[rr], off, 64);
            float c2 = __shfl_xor(c_run[rr], off, 64);
            float M = fmaxf(m_run[rr], m2);
            s_run[rr] = s_run[rr] * __expf(m_run[rr] - M) + s2 * __expf(m2 - M);
            m_run[rr] = M;
            A_run[rr] += A2;
            c_run[rr] += c2;
        }
    }

    if (tx == 0) {
#pragma unroll
        for (int rr = 0; rr < 8; ++rr) {
            const int i_g = i0 + arow + rr;
            stats[i_g * 8 + jc] = make_float4(m_run[rr], s_run[rr], A_run[rr], c_run[rr]);
        }
    }
}

// -------- Kernel 3: merge chunk partials per row, atomic global reduce --------
__global__ __launch_bounds__(256) void finalize_kernel(
    const float4* __restrict__ stats, const int* __restrict__ labels,
    float* __restrict__ accums, float* __restrict__ out) {
    const int tid = threadIdx.x;
    const int r = blockIdx.x * 256 + tid;   // 16 blocks x 256 rows

    float m = NEG_INF, sexp = 0.f, A = 0.f, cnt = 0.f;
#pragma unroll
    for (int c = 0; c < 8; ++c) {
        float4 v = stats[r * 8 + c];
        float M = fmaxf(m, v.x);
        sexp = sexp * __expf(m - M) + v.y * __expf(v.x - M);
        m = M;
        A += v.z;
        cnt += v.w;
    }
    float mlpp = 0.f, val = 0.f, nbv = 0.f;
    if (cnt > 0.5f) {   // numerator count is an integer; > EPS  <=>  >= 1
        float lse = m + __logf(sexp);
        mlpp = (A - cnt * lse) / (cnt + 1e-8f);
        val = 1.f;
        nbv = (labels[r] != 0) ? 1.f : 0.f;
    }

    __shared__ float red0[256], red1[256], red2[256];
    red0[tid] = mlpp; red1[tid] = val; red2[tid] = nbv;
    __syncthreads();
    for (int off = 128; off > 0; off >>= 1) {
        if (tid < off) {
            red0[tid] += red0[tid + off];
            red1[tid] += red1[tid + off];
            red2[tid] += red2[tid + off];
        }
        __syncthreads();
    }

    if (tid == 0) {
        atomicAdd(&accums[0], red0[0]);
        atomicAdd(&accums[1], red1[0]);
        atomicAdd(&accums[2], red2[0]);
        __threadfence();
        unsigned int old = atomicAdd((unsigned int*)&accums[3], 1u);
        if (old == 15u) {   // last block: all adds are visible in L2
            float S = atomicAdd(&accums[0], 0.f);
            float V = atomicAdd(&accums[1], 0.f);
            float NB = atomicAdd(&accums[2], 0.f);
            float loss = -S / V;
            out[0] = loss * NB / (NB + 1e-8f);
        }
    }
}

extern "C" void kernel_launch(void* const* d_in, const int* in_sizes, int n_in,
                              void* d_out, int out_size, void* d_ws, size_t ws_size,
                              hipStream_t stream) {
    const float* s = (const float*)d_in[0];
    const float* t = (const float*)d_in[1];
    const int* labels = (const int*)d_in[2];
    float* out = (float*)d_out;
    float* ws = (float*)d_ws;

    float* rs = ws;                         // 4096 floats
    float* rt = ws + 4096;                  // 4096 floats
    float* accums = ws + 8192;              // 8 floats (sum, valid, nbv, ticket)
    float4* stats = (float4*)(ws + 8208);   // 4096 * 8 float4 = 512 KB

    hipLaunchKernelGGL(norms_kernel, dim3(128), dim3(256), 0, stream,
                       s, t, rs, rt, accums);
    hipLaunchKernelGGL(logits_stats_kernel, dim3(256), dim3(256), 0, stream,
                       s, t, labels, rs, rt, stats);
    hipLaunchKernelGGL(finalize_kernel, dim3(16), dim3(256), 0, stream,
                       stats, labels, accums, out);
}